// Round 9
// baseline (529.117 us; speedup 1.0000x reference)
//
#include <hip/hip_runtime.h>

// T=512, B=512, K=8, V=5, H=30, NL=4, NLAB=3
#define TT 512
#define BB 512
#define KK 8
#define HH 30
#define GG 120   // 4*H
#define NLAYER 4
#define SPB 2    // samples per block: in-wave ILP (R9)

typedef _Float16 half2v __attribute__((ext_vector_type(2)));

__device__ __forceinline__ float rcp_f(float x) { return __builtin_amdgcn_rcpf(x); }
__device__ __forceinline__ float rdlane_f(float v, int l) {
    return __int_as_float(__builtin_amdgcn_readlane(__float_as_int(v), l));
}
__device__ __forceinline__ unsigned int rdlane_u(unsigned int v, int l) {
    return (unsigned int)__builtin_amdgcn_readlane((int)v, l);
}
__device__ __forceinline__ half2v as_h2(unsigned int u) {
    union { unsigned int u; half2v h; } c; c.u = u; return c.h;
}
// packed f32 FMA, broadcast operand in SGPR pair (attention epilogue)
__device__ __forceinline__ float2 pk_fma_s(float2 a, float2 bs, float2 c) {
    float2 d;
    asm("v_pk_fma_f32 %0, %1, %2, %3" : "=v"(d) : "v"(a), "s"(bs), "v"(c));
    return d;
}
// value from lane^32 partner (valid for lanes < 32; lanes >= 32 get lo value)
__device__ __forceinline__ float swap32_hi(float x) {
    float a = x, b = x;
    asm("v_permlane32_swap_b32 %0, %1" : "+v"(a), "+v"(b));
    return b;   // lanes<32: x[lane+32]
}

// One block = TWO samples; 4 waves = 4 LSTM layers, SYSTOLIC (barrier/epoch).
// R9 rationale: TLP is capped by the decomposition (512 samples x 4 waves =
// 2048 waves = exactly 2/SIMD) and R8's counters show each wave ~65% stalled
// with the co-resident wave filling poorly. Convert TLP -> in-wave ILP:
// each wave runs its layer for 2 independent samples, interleaved by the
// compiler, at 1 block/CU with the FULL register budget (waves_per_eu(1)).
// R3 tried this with f32 math and lost to AGPR parking (120 f32 weight regs,
// VGPR=136) + per-step LDS h round-trip; R8's engine removed both (f16
// weights = 60 regs, h in register hpk). Sync = R3-proven barrier systolic
// (epoch n, wave w runs group g=n-w; 8-step groups; 67 epochs) -- NOT the
// elastic protocol that raced at SPB=2 in R2. h state is registers-only, so
// no hring zero-init is needed at all. Per-sample math byte-identical to R8.
__global__ __launch_bounds__(256) __attribute__((amdgpu_waves_per_eu(1, 1)))
void rnn_fused(
    const int*   __restrict__ xin,  const float* __restrict__ wxin,
    const float* __restrict__ embed,
    const float* __restrict__ Wih,  const float* __restrict__ Whh,
    const float* __restrict__ bih,  const float* __restrict__ bhh,
    const float* __restrict__ W1,   const float* __restrict__ b1,
    const float* __restrict__ W2,   const float* __restrict__ b2,
    const float* __restrict__ fcW,  const float* __restrict__ fcb,
    float* __restrict__ out)
{
    __shared__ alignas(16) float hstore[SPB][TT * HH];            // layer-3 h (f32)
    __shared__ alignas(16) unsigned int seqring16[SPB][2][16][16];// pooled-embed f16 pairs
    __shared__ alignas(16) int   ringx[SPB][4][16][KK];           // x stream (wave-0)
    __shared__ alignas(16) float ringw[SPB][4][16][KK];
    __shared__ alignas(16) unsigned int hring16[SPB][3][16][16];  // layer->layer h f16
    __shared__ alignas(16) float re_s[5 * HH];                    // relu(embed)
    __shared__ alignas(16) float energy_s[TT];                    // reused per sample
    __shared__ float red_s[16];
    __shared__ float part_s[8][HH];
    __shared__ float pooled_s[HH];
    __shared__ float logits_s[3];

    const int tid  = threadIdx.x;
    const int wv   = tid >> 6;
    const int lane = tid & 63;
    const int b0   = blockIdx.x * SPB;

    // ---- preamble ----
    if (tid < 5 * HH) re_s[tid] = fmaxf(embed[tid], 0.0f);

    int4 hx[SPB]; float4 hw[SPB];                        // held x/w (wave0, lanes<32)
    #pragma unroll
    for (int s = 0; s < SPB; ++s) { hx[s] = {0,0,0,0}; hw[s] = {0,0,0,0}; }
    if (wv == 0 && lane < 32) {
        const int r = lane >> 1, hf = lane & 1;
        #pragma unroll
        for (int s = 0; s < SPB; ++s) {
            #pragma unroll
            for (int cc = 0; cc < 2; ++cc) {             // chunks 0,1 -> LDS
                long off = ((long)(16 * cc + r) * BB + (b0 + s)) * KK + hf * 4;
                *(int4*)(&ringx[s][cc][r][hf * 4])   = *(const int4*)(xin  + off);
                *(float4*)(&ringw[s][cc][r][hf * 4]) = *(const float4*)(wxin + off);
            }
            long off2 = ((long)(32 + r) * BB + (b0 + s)) * KK + hf * 4; // chunk 2 -> regs
            hx[s] = *(const int4*)(xin  + off2);
            hw[s] = *(const float4*)(wxin + off2);
        }
    }

    // ---- per-lane LSTM weights, XOR-32 gate layout, packed f16 pairs ----
    // half0 (lanes 0..31):  rowA = i-row q,    rowB = g-row q+60
    // half1 (lanes 32..63): rowA = f-row q+30, rowB = o-row q+90
    const int half = lane >> 5;
    const int q31  = lane & 31;
    const int qq   = (q31 < HH) ? q31 : (HH - 1);        // clamp dead lanes
    const int rA   = qq + half * HH;                     // 0..59
    const int rB   = rA + 60;                            // 60..119
    half2v wihA_h[15], wihB_h[15], whhA_h[15], whhB_h[15];
    {
        const float* WihL = Wih + wv * GG * HH;
        const float* WhhL = Whh + wv * GG * HH;
        #pragma unroll
        for (int kk = 0; kk < 15; ++kk) {
            float2 a0 = *(const float2*)(WihL + rA * HH + 2 * kk);
            float2 a1 = *(const float2*)(WihL + rB * HH + 2 * kk);
            float2 a2 = *(const float2*)(WhhL + rA * HH + 2 * kk);
            float2 a3 = *(const float2*)(WhhL + rB * HH + 2 * kk);
            wihA_h[kk][0] = (_Float16)a0.x; wihA_h[kk][1] = (_Float16)a0.y;
            wihB_h[kk][0] = (_Float16)a1.x; wihB_h[kk][1] = (_Float16)a1.y;
            whhA_h[kk][0] = (_Float16)a2.x; whhA_h[kk][1] = (_Float16)a2.y;
            whhB_h[kk][0] = (_Float16)a3.x; whhB_h[kk][1] = (_Float16)a3.y;
        }
    }
    const float biasA = bih[wv * GG + rA] + bhh[wv * GG + rA];
    const float biasB = bih[wv * GG + rB] + bhh[wv * GG + rB];
    const float mBneg = (lane < 32) ? -2.0f : -1.0f;     // half0: tanh via 2*sig(2x)-1
    const float aB    = (lane < 32) ?  2.0f :  1.0f;
    const float dB    = (lane < 32) ? -1.0f :  0.0f;

    __syncthreads();   // preamble visible (ringx/re_s)

    float c_val[SPB];
    unsigned int hpk[SPB];   // own h as packed f16 pair (even lanes)
    #pragma unroll
    for (int s = 0; s < SPB; ++s) { c_val[s] = 0.0f; hpk[s] = 0u; }

    auto do_step = [&](int t) {
        // x operands: packed f16 pairs from ring, uniform-address b128 reads
        unsigned int xu[SPB][16];
        #pragma unroll
        for (int s = 0; s < SPB; ++s) {
            const unsigned int* xsrc = (wv == 0)
                ? &seqring16[s][(t >> 4) & 1][t & 15][0]
                : &hring16[s][wv - 1][t & 15][0];
            uint4 q0 = ((const uint4*)xsrc)[0];
            uint4 q1 = ((const uint4*)xsrc)[1];
            uint4 q2 = ((const uint4*)xsrc)[2];
            uint4 q3 = ((const uint4*)xsrc)[3];
            xu[s][0]=q0.x; xu[s][1]=q0.y; xu[s][2]=q0.z; xu[s][3]=q0.w;
            xu[s][4]=q1.x; xu[s][5]=q1.y; xu[s][6]=q1.z; xu[s][7]=q1.w;
            xu[s][8]=q2.x; xu[s][9]=q2.y; xu[s][10]=q2.z; xu[s][11]=q2.w;
            xu[s][12]=q3.x; xu[s][13]=q3.y; xu[s][14]=q3.z; xu[s][15]=q3.w;
        }
        // h-side (chain-critical): readlanes of packed pairs; two samples
        // interleaved so each stream fills the other's hazards
        float ahA[SPB], ahB[SPB], ahA2[SPB], ahB2[SPB];
        #pragma unroll
        for (int s = 0; s < SPB; ++s) { ahA[s]=0.f; ahB[s]=0.f; ahA2[s]=0.f; ahB2[s]=0.f; }
        #pragma unroll
        for (int k = 0; k < 8; ++k) {
            #pragma unroll
            for (int s = 0; s < SPB; ++s) {
                const half2v hp = as_h2(rdlane_u(hpk[s], 2 * k));
                ahA[s] = __builtin_amdgcn_fdot2(whhA_h[k], hp, ahA[s], false);
                ahB[s] = __builtin_amdgcn_fdot2(whhB_h[k], hp, ahB[s], false);
            }
        }
        #pragma unroll
        for (int k = 8; k < 15; ++k) {
            #pragma unroll
            for (int s = 0; s < SPB; ++s) {
                const half2v hp = as_h2(rdlane_u(hpk[s], 2 * k));
                ahA2[s] = __builtin_amdgcn_fdot2(whhA_h[k], hp, ahA2[s], false);
                ahB2[s] = __builtin_amdgcn_fdot2(whhB_h[k], hp, ahB2[s], false);
            }
        }
        // x-side: independent of h, fills h-chain stalls
        float axA[SPB], axB[SPB];
        #pragma unroll
        for (int s = 0; s < SPB; ++s) { axA[s]=0.f; axB[s]=0.f; }
        #pragma unroll
        for (int k = 0; k < 15; ++k) {
            #pragma unroll
            for (int s = 0; s < SPB; ++s) {
                const half2v xp = as_h2(xu[s][k]);
                axA[s] = __builtin_amdgcn_fdot2(wihA_h[k], xp, axA[s], false);
                axB[s] = __builtin_amdgcn_fdot2(wihB_h[k], xp, axB[s], false);
            }
        }
        #pragma unroll
        for (int s = 0; s < SPB; ++s) {
            const float gA = (axA[s] + ahA[s]) + (ahA2[s] + biasA);  // i | f
            const float gB = (axB[s] + ahB[s]) + (ahB2[s] + biasB);  // g | o
            const float actA = rcp_f(1.0f + __expf(-gA));            // sigmoid
            const float sB   = rcp_f(1.0f + __expf(gB * mBneg));
            const float actB = fmaf(aB, sB, dB);                     // tanh | sigmoid
            const float fI = swap32_hi(actA);                        // f from lane+32
            const float oI = swap32_hi(actB);                        // o from lane+32
            c_val[s] = fmaf(fI, c_val[s], actA * actB);              // lanes 0..29
            const float tC = fmaf(2.0f, rcp_f(1.0f + __expf(-2.0f * c_val[s])), -1.0f);
            const float hv = oI * tC;
            // pack f16 pair: own (lo) | quad-perm partner (hi); even lanes valid
            union { _Float16 f[2]; unsigned int u; } cv; cv.u = 0;
            cv.f[0] = (_Float16)hv;
            const unsigned int hu  = cv.u;
            const unsigned int hup = (unsigned int)__builtin_amdgcn_mov_dpp(
                                         (int)hu, 0xB1, 0xF, 0xF, true); // [1,0,3,2]
            hpk[s] = hu | (hup << 16);
            if (lane < HH) {
                if (wv == NLAYER - 1) hstore[s][t * HH + lane] = hv;           // f32
                else if (!(lane & 1)) hring16[s][wv][t & 15][lane >> 1] = hpk[s];
            }
        }
    };

    // ---- systolic recurrence: epoch n, wave w runs group g=n-w (8 steps) ----
    const int NGROUP = TT / 8;                           // 64
    const int NEPOCH = NGROUP + NLAYER - 1;              // 67
    for (int n = 0; n < NEPOCH; ++n) {
        const int g = n - wv;
        if (g >= 0 && g < NGROUP) {
            const int T0 = 8 * g;
            if (wv == 0 && (T0 & 15) == 0) {             // chunk boundary (private)
                const int c = T0 >> 4;
                if (lane < 32) {
                    const int r = lane >> 1, hf = lane & 1;
                    #pragma unroll
                    for (int s = 0; s < SPB; ++s) {
                        if (c <= 29) {                   // commit chunk c+2
                            const int sl = (c + 2) & 3;
                            *(int4*)(&ringx[s][sl][r][hf * 4])   = hx[s];
                            *(float4*)(&ringw[s][sl][r][hf * 4]) = hw[s];
                        }
                        if (c <= 28) {                   // load chunk c+3
                            long off = ((long)(16 * (c + 3) + r) * BB + (b0 + s)) * KK + hf * 4;
                            hx[s] = *(const int4*)(xin  + off);
                            hw[s] = *(const float4*)(wxin + off);
                        }
                    }
                }
                const int sl = c & 3, par = c & 1;       // gather pooled chunk c
                #pragma unroll
                for (int s = 0; s < SPB; ++s) {
                    #pragma unroll
                    for (int rr = 0; rr < 8; ++rr) {
                        const int o = lane + rr * 64;
                        if (o < 480) {
                            const int tr = o / HH, j = o - tr * HH;
                            int4   xa = *(const int4*)(&ringx[s][sl][tr][0]);
                            int4   xb = *(const int4*)(&ringx[s][sl][tr][4]);
                            float4 wa = *(const float4*)(&ringw[s][sl][tr][0]);
                            float4 wb = *(const float4*)(&ringw[s][sl][tr][4]);
                            float acc = re_s[xa.x * HH + j] * wa.x;
                            acc = fmaf(re_s[xa.y * HH + j], wa.y, acc);
                            acc = fmaf(re_s[xa.z * HH + j], wa.z, acc);
                            acc = fmaf(re_s[xa.w * HH + j], wa.w, acc);
                            acc = fmaf(re_s[xb.x * HH + j], wb.x, acc);
                            acc = fmaf(re_s[xb.y * HH + j], wb.y, acc);
                            acc = fmaf(re_s[xb.z * HH + j], wb.z, acc);
                            acc = fmaf(re_s[xb.w * HH + j], wb.w, acc);
                            ((_Float16*)&seqring16[s][par][tr][0])[j] =
                                (_Float16)(acc * 0.125f);
                        }
                    }
                }
                __threadfence_block();                   // gather visible to own reads
            }
            #pragma unroll 1
            for (int tt = 0; tt < 8; ++tt)
                do_step(T0 + tt);
        }
        __syncthreads();                                 // orders ALL cross-wave edges
    }

    // (final epoch barrier also covers hstore completion)

    // ---- attention weights (registers, reused for both samples) ----
    const float* W1p = W1;
    const float* b1p = b1;
    const float* W2p = W2;
    asm volatile("" : "+v"(W1p), "+v"(b1p), "+v"(W2p)); // block hoist above loop

    float w1cx[15], w1cy[15];                            // W1 column `lane`
    #pragma unroll
    for (int k = 0; k < 15; ++k) {
        w1cx[k] = W1p[(2 * k) * 64 + lane];
        w1cy[k] = W1p[(2 * k + 1) * 64 + lane];
    }
    const float b1v = b1p[lane];
    const float w2v = W2p[lane];
    const float b2v = b2[0];

    for (int s = 0; s < SPB; ++s) {
        // ---- attention, t-per-lane: e_t = relu(h_t @ W1 + b1) @ W2 + b2 ----
        #pragma unroll
        for (int pass = 0; pass < 2; ++pass) {
            const int t = wv * 128 + pass * 64 + lane;   // each lane owns one t
            float2 h2[15];
            #pragma unroll
            for (int k = 0; k < 15; ++k)
                h2[k] = *(const float2*)(&hstore[s][t * HH + 2 * k]);
            float e = b2v;
            for (int u = 0; u < 64; ++u) {               // W1 broadcast via readlane
                float2 acc = {0.f, 0.f};
                #pragma unroll
                for (int k = 0; k < 15; ++k) {
                    float2 wp;
                    wp.x = rdlane_f(w1cx[k], u);
                    wp.y = rdlane_f(w1cy[k], u);
                    acc = pk_fma_s(h2[k], wp, acc);
                }
                const float su = acc.x + acc.y + rdlane_f(b1v, u);
                e = fmaf(fmaxf(su, 0.0f), rdlane_f(w2v, u), e);
            }
            energy_s[t] = e;
        }
        __syncthreads();

        // ---- softmax over T ----
        float mx = -3.0e38f;
        for (int i = tid; i < TT; i += 256) mx = fmaxf(mx, energy_s[i]);
        #pragma unroll
        for (int m = 1; m < 64; m <<= 1) mx = fmaxf(mx, __shfl_xor(mx, m, 64));
        if (lane == 0) red_s[wv] = mx;
        __syncthreads();
        mx = fmaxf(fmaxf(red_s[0], red_s[1]), fmaxf(red_s[2], red_s[3]));
        float ssum = 0.0f;
        for (int i = tid; i < TT; i += 256) {
            float ev = __expf(energy_s[i] - mx);
            energy_s[i] = ev;
            ssum += ev;
        }
        #pragma unroll
        for (int m = 1; m < 64; m <<= 1) ssum += __shfl_xor(ssum, m, 64);
        if (lane == 0) red_s[8 + wv] = ssum;
        __syncthreads();
        const float invS = rcp_f(red_s[8] + red_s[9] + red_s[10] + red_s[11]);

        // ---- pooled_j = sum_t softmax_t * h[t][j] ----
        {
            const int g = tid >> 5, jj = tid & 31;
            if (jj < HH) {
                float part = 0.0f;
                for (int t = g; t < TT; t += 8)
                    part = fmaf(energy_s[t] * invS, hstore[s][t * HH + jj], part);
                part_s[g][jj] = part;
            }
        }
        __syncthreads();
        if (tid < HH) {
            float pv = 0.0f;
            #pragma unroll
            for (int q = 0; q < 8; ++q) pv += part_s[q][tid];
            pooled_s[tid] = pv;
        }
        __syncthreads();

        // ---- FC (30->3) + softmax ----
        if (tid < 3) {
            float acc = fcb[tid];
            #pragma unroll
            for (int k = 0; k < HH; ++k) acc = fmaf(pooled_s[k], fcW[k * 3 + tid], acc);
            logits_s[tid] = acc;
        }
        __syncthreads();
        if (tid == 0) {
            float l0 = logits_s[0], l1 = logits_s[1], l2 = logits_s[2];
            float m3 = fmaxf(l0, fmaxf(l1, l2));
            float e0 = __expf(l0 - m3), e1 = __expf(l1 - m3), e2 = __expf(l2 - m3);
            float inv = rcp_f(e0 + e1 + e2);
            const int bo = (b0 + s) * 3;
            out[bo + 0] = e0 * inv; out[bo + 1] = e1 * inv; out[bo + 2] = e2 * inv;
        }
        __syncthreads();   // protect energy_s/red_s/part_s/pooled_s/logits_s reuse
    }
}

extern "C" void kernel_launch(void* const* d_in, const int* in_sizes, int n_in,
                              void* d_out, int out_size, void* d_ws, size_t ws_size,
                              hipStream_t stream)
{
    (void)in_sizes; (void)n_in; (void)d_ws; (void)ws_size; (void)out_size;
    rnn_fused<<<BB / SPB, 256, 0, stream>>>(
        (const int*)  d_in[0],  (const float*)d_in[1],  (const float*)d_in[2],
        (const float*)d_in[3],  (const float*)d_in[4],  (const float*)d_in[5],
        (const float*)d_in[6],  (const float*)d_in[7],  (const float*)d_in[8],
        (const float*)d_in[9],  (const float*)d_in[10], (const float*)d_in[11],
        (const float*)d_in[12], (float*)d_out);
}